// Round 1
// 145.844 us; speedup vs baseline: 1.0186x; 1.0186x over previous
//
#include <hip/hip_runtime.h>
#include <math.h>

// Problem constants
#define HD    64     // hidden
#define NIN   1535   // input nodes
#define NN    1536   // total nodes
#define BB    32     // batch
#define BN_EPS 1e-5f
#define CH    64     // rows per chunk
#define NCH   24     // chunks per batch (24*64 = 1536)

// Workspace layout (floats):
//   M_ws [768], S_ws [768], vec_ws [768][64], ss [32][64], WAVT [4096], bAV [64]
#define WS_M     0
#define WS_S     768
#define WS_V     1536
#define WS_SS    50688   // 1536 + 768*64
#define WS_WAVT  52736   // 50688 + 2048
#define WS_BAV   56832   // 52736 + 4096

// ================================================================ k_main
// Per block: batch b, chunk c (64 rows). Encode rows (fc1+relu, fc2+relu;
// output node uses enc path), compute per-row attention score sk = h2·u
// (the i-dependent score term is constant over the softmax axis and the
// bK·wQKk constant cancels in softmax -> both dropped), and emit a
// flash-style partial (m, sum_e, sum_e*h) for this chunk.
__global__ __launch_bounds__(256) void k_main(
    const float* __restrict__ xx,   // [B,NIN,8]
    const float* __restrict__ yy,   // [B,NIN]
    const float* __restrict__ oxx,  // [B,1,8]
    const float* __restrict__ W1, const float* __restrict__ b1,
    const float* __restrict__ W2, const float* __restrict__ b2,
    const float* __restrict__ Wenc, const float* __restrict__ benc,
    const float* __restrict__ WK, const float* __restrict__ wQKk,
    float* __restrict__ ws) {
  __shared__ float W1s[576];          // [64][9] stride 9 (odd -> 2-way, free)
  __shared__ float b1s[64], b2s[64], bencs[64], us[64];
  __shared__ float Wencs[512];        // [64][8]
  __shared__ float W2Ts[64 * 65];     // W2T[k][h] at k*65+h (pad -> no conflicts)
  __shared__ float xs[512];           // [64 rows][8]
  __shared__ float ys[64];
  __shared__ float h1s[4][64];        // per-wave fc1 output
  __shared__ float h2s[64 * 64];      // chunk node features
  __shared__ float sks[64], e_s[64], rbuf[256], red0[1];

  const int t = threadIdx.x;
  const int blk = blockIdx.x;
  const int b = blk & 31;
  const int c = blk >> 5;
  const int pp = b * NCH + c;        // partial index

  // ---- stage weights + inputs (coalesced) ----
  for (int e = t; e < 576; e += 256) W1s[e] = W1[e];
  for (int e = t; e < 512; e += 256) Wencs[e] = Wenc[e];
  for (int e = t; e < 4096; e += 256) {
    int h = e >> 6, k = e & 63;
    W2Ts[k * 65 + h] = W2[e];
  }
  for (int e = t; e < 512; e += 256) {
    int j = e >> 3, k = e & 7;
    int r0 = c * CH + j;
    xs[e] = (r0 < NIN) ? xx[(size_t)b * (NIN * 8) + (size_t)r0 * 8 + k]
                       : oxx[b * 8 + k];
  }
  if (t < 64) {
    b1s[t] = b1[t]; b2s[t] = b2[t]; bencs[t] = benc[t];
    int r0 = c * CH + t;
    ys[t] = (r0 < NIN) ? yy[b * NIN + r0] : 0.f;
    // u = WK^T @ wQKk (coalesced per iter; fully unrolled -> loads pipeline)
    float a = 0.f;
    #pragma unroll
    for (int h0 = 0; h0 < 64; h0++) a += wQKk[h0] * WK[h0 * 64 + t];
    us[t] = a;
  }
  __syncthreads();

  const int w = t >> 6, lane = t & 63;
  float* h1w = h1s[w];

  // each lane caches its W2 column (W2[lane][k], k=0..63) in VGPRs once
  float w2r[64];
  #pragma unroll
  for (int k = 0; k < 64; k++) w2r[k] = W2Ts[k * 65 + lane];

  // ---- 16 rows per wave ----
  for (int rr = 0; rr < 16; rr++) {
    int j = w * 16 + rr;
    int r0 = c * CH + j;
    const float* xr = xs + j * 8;
    float h2;
    if (r0 < NIN) {                       // wave-uniform branch
      const float* wr = W1s + lane * 9;
      float a = b1s[lane];
      a += xr[0] * wr[0] + xr[1] * wr[1] + xr[2] * wr[2] + xr[3] * wr[3];
      a += xr[4] * wr[4] + xr[5] * wr[5] + xr[6] * wr[6] + xr[7] * wr[7];
      a += ys[j] * wr[8];
      h1w[lane] = fmaxf(a, 0.f);          // wave-synchronous LDS
      float a0 = b2s[lane], a1 = 0.f;
      #pragma unroll
      for (int k = 0; k < 64; k += 4) {
        float4 hv = *(const float4*)(h1w + k);   // broadcast b128
        a0 += hv.x * w2r[k]     + hv.z * w2r[k + 2];
        a1 += hv.y * w2r[k + 1] + hv.w * w2r[k + 3];
      }
      h2 = fmaxf(a0 + a1, 0.f);
    } else {                              // output node: single enc layer
      const float* wr = Wencs + lane * 8;
      float a = bencs[lane];
      #pragma unroll
      for (int k = 0; k < 8; k++) a += xr[k] * wr[k];
      h2 = fmaxf(a, 0.f);
    }
    h2s[j * 64 + lane] = h2;
    // score = h2 . u  (wave reduce)
    float p = h2 * us[lane];
    p += __shfl_down(p, 32); p += __shfl_down(p, 16); p += __shfl_down(p, 8);
    p += __shfl_down(p, 4);  p += __shfl_down(p, 2);  p += __shfl_down(p, 1);
    if (lane == 0) sks[j] = p;
  }
  __syncthreads();

  // ---- chunk softmax partial ----
  if (t < 64) {
    float m = sks[t];
    m = fmaxf(m, __shfl_down(m, 32)); m = fmaxf(m, __shfl_down(m, 16));
    m = fmaxf(m, __shfl_down(m, 8));  m = fmaxf(m, __shfl_down(m, 4));
    m = fmaxf(m, __shfl_down(m, 2));  m = fmaxf(m, __shfl_down(m, 1));
    if (t == 0) red0[0] = m;
  }
  __syncthreads();
  float M = red0[0];
  if (t < 64) {
    float e = expf(sks[t] - M);
    e_s[t] = e;
    float s = e;
    s += __shfl_down(s, 32); s += __shfl_down(s, 16); s += __shfl_down(s, 8);
    s += __shfl_down(s, 4);  s += __shfl_down(s, 2);  s += __shfl_down(s, 1);
    if (t == 0) { ws[WS_M + pp] = M; ws[WS_S + pp] = s; }
  }
  __syncthreads();
  // vec = sum_j e_j * h2[j][:]
  {
    float acc = 0.f;
    for (int j = w; j < 64; j += 4) acc += e_s[j] * h2s[j * 64 + lane];
    rbuf[t] = acc;
    __syncthreads();
    if (t < 64)
      ws[WS_V + pp * 64 + t] =
          rbuf[t] + rbuf[64 + t] + rbuf[128 + t] + rbuf[192 + t];
  }
}

// ================================================================ k_comb
// 33 blocks. Blocks 0..31: combine the NCH softmax partials of one batch
// into ss[b][64] (parallel across CUs -> the cross-XCD partial reads that
// made the old single-block k_tail latency-bound now happen concurrently).
// Block 32: fold WAVT = (WA@WV)^T and bAV (no dependency on k_main's data,
// so it rides along in parallel instead of sitting on the serial path).
__global__ __launch_bounds__(256) void k_comb(
    const float* __restrict__ WV, const float* __restrict__ bV,
    const float* __restrict__ WA, const float* __restrict__ bA,
    float* __restrict__ ws) {
  __shared__ float WAs[64 * 65];   // WA[h][m] at h*65+m
  __shared__ float WVs[4096];      // WV[m][k]
  __shared__ float Ml[NCH], Sl[NCH], wexp[NCH];
  __shared__ float red[256];
  __shared__ float MbS, iSbS;
  const int t = threadIdx.x;

  if (blockIdx.x == 32) {
    // ---- WAVT + bAV ----
    for (int e = t; e < 4096; e += 256) {
      int h = e >> 6, m = e & 63;
      WAs[h * 65 + m] = WA[e];
      WVs[e] = WV[e];
    }
    __syncthreads();
    if (t < 64) {
      float a = bA[t];
      #pragma unroll
      for (int k = 0; k < 64; k++) a += WAs[t * 65 + k] * bV[k];
      ws[WS_BAV + t] = a;
    }
    // WAVT[k][h]: thread (kg=t>>6, h=t&63) computes 16 k's with ILP-16 accs
    int kg = t >> 6, h = t & 63;
    float acc[16];
    #pragma unroll
    for (int kk = 0; kk < 16; kk++) acc[kk] = 0.f;
    for (int m = 0; m < 64; m++) {
      float wa = WAs[h * 65 + m];
      const float4* wv = (const float4*)(WVs + m * 64 + kg * 16);
      float4 w0 = wv[0], w1 = wv[1], w2 = wv[2], w3 = wv[3];
      acc[0]  += wa * w0.x; acc[1]  += wa * w0.y; acc[2]  += wa * w0.z; acc[3]  += wa * w0.w;
      acc[4]  += wa * w1.x; acc[5]  += wa * w1.y; acc[6]  += wa * w1.z; acc[7]  += wa * w1.w;
      acc[8]  += wa * w2.x; acc[9]  += wa * w2.y; acc[10] += wa * w2.z; acc[11] += wa * w2.w;
      acc[12] += wa * w3.x; acc[13] += wa * w3.y; acc[14] += wa * w3.z; acc[15] += wa * w3.w;
    }
    #pragma unroll
    for (int kk = 0; kk < 16; kk++) ws[WS_WAVT + (kg * 16 + kk) * 64 + h] = acc[kk];
    return;
  }

  // ---- one batch's softmax-partial combine ----
  const int bb = blockIdx.x;
  if (t < NCH) {
    Ml[t] = ws[WS_M + bb * NCH + t];
    Sl[t] = ws[WS_S + bb * NCH + t];
  }
  __syncthreads();
  if (t == 0) {
    float m = -1e30f;
    for (int cc = 0; cc < NCH; cc++) m = fmaxf(m, Ml[cc]);
    MbS = m;
  }
  __syncthreads();
  if (t < NCH) wexp[t] = expf(Ml[t] - MbS);
  __syncthreads();
  if (t == 0) {
    float s = 0.f;
    for (int cc = 0; cc < NCH; cc++) s += Sl[cc] * wexp[cc];
    iSbS = 1.0f / s;
  }
  __syncthreads();
  // ss[bb][h] = (sum_c wexp_c * vec_c[h]) / S_b
  {
    int cg = t >> 6, h = t & 63;
    float acc = 0.f;
    for (int cc = cg; cc < NCH; cc += 4)
      acc += wexp[cc] * ws[WS_V + (size_t)(bb * NCH + cc) * 64 + h];
    red[t] = acc;
    __syncthreads();
    if (t < 64)
      ws[WS_SS + bb * 64 + t] =
          (red[t] + red[64 + t] + red[128 + t] + red[192 + t]) * iSbS;
  }
}

// ================================================================ k_fin
// One block, 1024 threads (16 waves for latency hiding; the old k_tail had
// only 4). Loads the precomputed WAVT/bAV/ss (24 KB, L2-hot), runs the
// inherently-serial 4 rounds (z = st@WAVT + bAV; BN over batch; relu)
// entirely in LDS, then the heads.
__global__ __launch_bounds__(1024) void k_fin(
    const float* __restrict__ ws,
    const float* __restrict__ gamma, const float* __restrict__ beta,
    const float* __restrict__ Wmu, const float* __restrict__ bmu,
    const float* __restrict__ Wsig, const float* __restrict__ bsig,
    float* __restrict__ out) {
  __shared__ float WAVT[4096];     // WAVT[k][h]
  __shared__ float bAVs[64];
  __shared__ float st[32 * 66];    // stride 66: bank = (2b+k)%32, conflict-free
  __shared__ float zs[32 * 66];
  __shared__ float scs[64], shs[64];
  __shared__ float gammas[64], betas[64], wmus[64], wsigs[64];
  const int t = threadIdx.x;

  for (int e = t; e < 4096; e += 1024) WAVT[e] = ws[WS_WAVT + e];
  if (t >= 1024 - 64) {            // a different wave than the ss loader
    int h = t - (1024 - 64);
    bAVs[h]   = ws[WS_BAV + h];
    gammas[h] = gamma[h];
    betas[h]  = beta[h];
    wmus[h]   = Wmu[h];
    wsigs[h]  = Wsig[h];
  }
  for (int e = t; e < 2048; e += 1024) {
    int bb = e >> 6, hh = e & 63;
    st[bb * 66 + hh] = ws[WS_SS + e];
  }
  __syncthreads();

  // ---- 4 rounds: z = st@WAVT + bAV; BN over batch; relu ----
  for (int r = 0; r < 4; r++) {
    {
      int bb = t >> 5, hg = t & 31;       // each thread: 2 h's (hg, hg+32)
      float a0 = bAVs[hg], a1 = bAVs[hg + 32];
      #pragma unroll 16
      for (int k = 0; k < 64; k++) {
        float v = st[bb * 66 + k];
        a0 += v * WAVT[k * 64 + hg];
        a1 += v * WAVT[k * 64 + hg + 32];
      }
      zs[bb * 66 + hg]      = a0;
      zs[bb * 66 + hg + 32] = a1;
    }
    __syncthreads();
    if (t < 64) {
      float s1 = 0.f;
      #pragma unroll
      for (int bb2 = 0; bb2 < BB; bb2++) s1 += zs[bb2 * 66 + t];
      float mu = s1 * (1.0f / BB);
      float s2 = 0.f;
      #pragma unroll
      for (int bb2 = 0; bb2 < BB; bb2++) {
        float d = zs[bb2 * 66 + t] - mu;
        s2 += d * d;
      }
      float inv = gammas[t] / sqrtf(s2 * (1.0f / BB) + BN_EPS);
      scs[t] = inv;
      shs[t] = betas[t] - mu * inv;
    }
    __syncthreads();
    for (int e = t; e < BB * 64; e += 1024) {
      int bb2 = e >> 6, hh = e & 63;
      st[bb2 * 66 + hh] = fmaxf(zs[bb2 * 66 + hh] * scs[hh] + shs[hh], 0.f);
    }
    __syncthreads();
  }

  // heads (agg = max over identical nodes = state itself)
  if (t < BB) {
    const float* nr = st + t * 66;
    float m = bmu[0], sg = bsig[0];
    #pragma unroll 8
    for (int h = 0; h < 64; h++) {
      float v = nr[h];
      m += v * wmus[h];
      sg += v * wsigs[h];
    }
    out[t] = m;
    out[BB + t] = sg * sg + 0.01f;
  }
}

// ================================================================ launch
extern "C" void kernel_launch(void* const* d_in, const int* in_sizes, int n_in,
                              void* d_out, int out_size, void* d_ws, size_t ws_size,
                              hipStream_t stream) {
  const float* xx   = (const float*)d_in[0];
  const float* yy   = (const float*)d_in[1];
  const float* oxx  = (const float*)d_in[2];
  const float* W1   = (const float*)d_in[3];
  const float* b1   = (const float*)d_in[4];
  const float* W2   = (const float*)d_in[5];
  const float* b2   = (const float*)d_in[6];
  const float* Wenc = (const float*)d_in[7];
  const float* benc = (const float*)d_in[8];
  // d_in[9]=WQ, [10]=bQ, [15]=wQKq, [17]=bQK: provably unused (the
  // i-dependent score term is constant over the softmax axis; bK·wQKk
  // cancels too, so d_in[12]=bK is also unused).
  const float* WK   = (const float*)d_in[11];
  const float* WV   = (const float*)d_in[13];
  const float* bV   = (const float*)d_in[14];
  const float* wQKk = (const float*)d_in[16];
  const float* WA   = (const float*)d_in[18];
  const float* bA   = (const float*)d_in[19];
  const float* gamma= (const float*)d_in[20];
  const float* beta = (const float*)d_in[21];
  const float* Wmu  = (const float*)d_in[22];
  const float* bmu  = (const float*)d_in[23];
  const float* Wsig = (const float*)d_in[24];
  const float* bsig = (const float*)d_in[25];

  float* ws  = (float*)d_ws;
  float* out = (float*)d_out;

  k_main<<<BB * NCH, 256, 0, stream>>>(xx, yy, oxx, W1, b1, W2, b2, Wenc, benc,
                                       WK, wQKk, ws);
  k_comb<<<33, 256, 0, stream>>>(WV, bV, WA, bA, ws);
  k_fin<<<1, 1024, 0, stream>>>(ws, gamma, beta, Wmu, bmu, Wsig, bsig, out);
}

// Round 2
// 137.357 us; speedup vs baseline: 1.0815x; 1.0618x over previous
//
#include <hip/hip_runtime.h>
#include <math.h>

// Problem constants
#define HD    64     // hidden
#define NIN   1535   // input nodes
#define NN    1536   // total nodes
#define BB    32     // batch
#define BN_EPS 1e-5f
#define CH    64     // rows per chunk
#define NCH   24     // chunks per batch (24*64 = 1536)

// Workspace layout (floats): M_ws [768], S_ws [768], vec_ws [768][64]
#define WS_M     0
#define WS_S     768
#define WS_V     1536

// ================================================================ k_main
// Per block: batch b, chunk c (64 rows). Encode rows (fc1+relu, fc2+relu;
// output node uses enc path), compute per-row attention score sk = h2·u
// (the i-dependent score term is constant over the softmax axis and the
// bK·wQKk constant cancels in softmax -> both dropped), and emit a
// flash-style partial (m, sum_e, sum_e*h) for this chunk.
__global__ __launch_bounds__(256) void k_main(
    const float* __restrict__ xx,   // [B,NIN,8]
    const float* __restrict__ yy,   // [B,NIN]
    const float* __restrict__ oxx,  // [B,1,8]
    const float* __restrict__ W1, const float* __restrict__ b1,
    const float* __restrict__ W2, const float* __restrict__ b2,
    const float* __restrict__ Wenc, const float* __restrict__ benc,
    const float* __restrict__ WK, const float* __restrict__ wQKk,
    float* __restrict__ ws) {
  __shared__ float W1s[576];          // [64][9] stride 9 (odd -> 2-way, free)
  __shared__ float b1s[64], b2s[64], bencs[64], us[64];
  __shared__ float Wencs[512];        // [64][8]
  __shared__ float W2Ts[64 * 65];     // W2T[k][h] at k*65+h (pad -> no conflicts)
  __shared__ float xs[512];           // [64 rows][8]
  __shared__ float ys[64];
  __shared__ float h1s[4][64];        // per-wave fc1 output
  __shared__ float h2s[64 * 64];      // chunk node features
  __shared__ float sks[64], e_s[64], rbuf[256], red0[1];

  const int t = threadIdx.x;
  const int blk = blockIdx.x;
  const int b = blk & 31;
  const int c = blk >> 5;
  const int pp = b * NCH + c;        // partial index

  // ---- stage weights + inputs (coalesced) ----
  for (int e = t; e < 576; e += 256) W1s[e] = W1[e];
  for (int e = t; e < 512; e += 256) Wencs[e] = Wenc[e];
  for (int e = t; e < 4096; e += 256) {
    int h = e >> 6, k = e & 63;
    W2Ts[k * 65 + h] = W2[e];
  }
  for (int e = t; e < 512; e += 256) {
    int j = e >> 3, k = e & 7;
    int r0 = c * CH + j;
    xs[e] = (r0 < NIN) ? xx[(size_t)b * (NIN * 8) + (size_t)r0 * 8 + k]
                       : oxx[b * 8 + k];
  }
  if (t < 64) {
    b1s[t] = b1[t]; b2s[t] = b2[t]; bencs[t] = benc[t];
    int r0 = c * CH + t;
    ys[t] = (r0 < NIN) ? yy[b * NIN + r0] : 0.f;
    // u = WK^T @ wQKk (coalesced per iter; fully unrolled -> loads pipeline)
    float a = 0.f;
    #pragma unroll
    for (int h0 = 0; h0 < 64; h0++) a += wQKk[h0] * WK[h0 * 64 + t];
    us[t] = a;
  }
  __syncthreads();

  const int w = t >> 6, lane = t & 63;
  float* h1w = h1s[w];

  // each lane caches its W2 column (W2[lane][k], k=0..63) in VGPRs once
  float w2r[64];
  #pragma unroll
  for (int k = 0; k < 64; k++) w2r[k] = W2Ts[k * 65 + lane];

  // ---- 16 rows per wave ----
  for (int rr = 0; rr < 16; rr++) {
    int j = w * 16 + rr;
    int r0 = c * CH + j;
    const float* xr = xs + j * 8;
    float h2;
    if (r0 < NIN) {                       // wave-uniform branch
      const float* wr = W1s + lane * 9;
      float a = b1s[lane];
      a += xr[0] * wr[0] + xr[1] * wr[1] + xr[2] * wr[2] + xr[3] * wr[3];
      a += xr[4] * wr[4] + xr[5] * wr[5] + xr[6] * wr[6] + xr[7] * wr[7];
      a += ys[j] * wr[8];
      h1w[lane] = fmaxf(a, 0.f);          // wave-synchronous LDS
      float a0 = b2s[lane], a1 = 0.f;
      #pragma unroll
      for (int k = 0; k < 64; k += 4) {
        float4 hv = *(const float4*)(h1w + k);   // broadcast b128
        a0 += hv.x * w2r[k]     + hv.z * w2r[k + 2];
        a1 += hv.y * w2r[k + 1] + hv.w * w2r[k + 3];
      }
      h2 = fmaxf(a0 + a1, 0.f);
    } else {                              // output node: single enc layer
      const float* wr = Wencs + lane * 8;
      float a = bencs[lane];
      #pragma unroll
      for (int k = 0; k < 8; k++) a += xr[k] * wr[k];
      h2 = fmaxf(a, 0.f);
    }
    h2s[j * 64 + lane] = h2;
    // score = h2 . u  (wave reduce)
    float p = h2 * us[lane];
    p += __shfl_down(p, 32); p += __shfl_down(p, 16); p += __shfl_down(p, 8);
    p += __shfl_down(p, 4);  p += __shfl_down(p, 2);  p += __shfl_down(p, 1);
    if (lane == 0) sks[j] = p;
  }
  __syncthreads();

  // ---- chunk softmax partial ----
  if (t < 64) {
    float m = sks[t];
    m = fmaxf(m, __shfl_down(m, 32)); m = fmaxf(m, __shfl_down(m, 16));
    m = fmaxf(m, __shfl_down(m, 8));  m = fmaxf(m, __shfl_down(m, 4));
    m = fmaxf(m, __shfl_down(m, 2));  m = fmaxf(m, __shfl_down(m, 1));
    if (t == 0) red0[0] = m;
  }
  __syncthreads();
  float M = red0[0];
  if (t < 64) {
    float e = expf(sks[t] - M);
    e_s[t] = e;
    float s = e;
    s += __shfl_down(s, 32); s += __shfl_down(s, 16); s += __shfl_down(s, 8);
    s += __shfl_down(s, 4);  s += __shfl_down(s, 2);  s += __shfl_down(s, 1);
    if (t == 0) { ws[WS_M + pp] = M; ws[WS_S + pp] = s; }
  }
  __syncthreads();
  // vec = sum_j e_j * h2[j][:]
  {
    float acc = 0.f;
    for (int j = w; j < 64; j += 4) acc += e_s[j] * h2s[j * 64 + lane];
    rbuf[t] = acc;
    __syncthreads();
    if (t < 64)
      ws[WS_V + pp * 64 + t] =
          rbuf[t] + rbuf[64 + t] + rbuf[128 + t] + rbuf[192 + t];
  }
}

// ================================================================ k_post
// ONE kernel for the whole serial tail, 1024 threads (16 waves).
//  stage 0: stage WA/WV/partials to LDS.
//  stage 1 (split, no internal barriers):
//    threads 512..1023: WAVT = (WA@WV)^T fold + bAV  (runs concurrently)
//    threads   0..511 : per-batch softmax-partial combine -> st[32][64]
//  stage 2: each thread caches its WAVT column in 64 VGPRs (fully
//    unrolled -> static indices, stays in registers), then 4 rounds of
//    {z = st@WAVT + bAV (st read as broadcast float4), BN over batch,
//    relu}, then heads via shuffle reduction.
// st/zs stride 68: 16B-aligned rows for float4 AND <=2-way banks on all
// access patterns used here.
#define STS 68
__global__ __launch_bounds__(1024) void k_post(
    const float* __restrict__ ws,
    const float* __restrict__ WV, const float* __restrict__ bV,
    const float* __restrict__ WA, const float* __restrict__ bA,
    const float* __restrict__ gamma, const float* __restrict__ beta,
    const float* __restrict__ Wmu, const float* __restrict__ bmu,
    const float* __restrict__ Wsig, const float* __restrict__ bsig,
    float* __restrict__ out) {
  __shared__ float WAs[64 * 65];   // WA[h][m] at h*65+m
  __shared__ float WVs[4096];      // WV[m][k]
  __shared__ float WAVT[4096];     // WAVT[k][h]
  __shared__ float Ml[768], Sl[768];
  __shared__ float st[32 * STS], zs[32 * STS];
  __shared__ float bAVs[64], scs[64], shs[64];
  __shared__ float gammas[64], betas[64], wmus[64], wsigs[64], bVs[64];
  const int t = threadIdx.x;

  // ---- stage 0 ----
  for (int e = t; e < 4096; e += 1024) {
    int h = e >> 6, m = e & 63;
    WAs[h * 65 + m] = WA[e];
    WVs[e] = WV[e];
  }
  for (int p = t; p < 768; p += 1024) {
    Ml[p] = ws[WS_M + p];
    Sl[p] = ws[WS_S + p];
  }
  if (t < 64) {
    gammas[t] = gamma[t]; betas[t] = beta[t];
    wmus[t] = Wmu[t]; wsigs[t] = Wsig[t]; bVs[t] = bV[t];
  }
  __syncthreads();

  // ---- stage 1 (split halves, no internal sync needed) ----
  if (t >= 512) {
    int w2 = t - 512;
    int kg = w2 >> 6;            // wave-uniform -> WVs reads broadcast
    int h  = w2 & 63;
    float acc[8];
    #pragma unroll
    for (int j = 0; j < 8; j++) acc[j] = 0.f;
    for (int m = 0; m < 64; m++) {
      float wa = WAs[h * 65 + m];
      const float4* wv = (const float4*)(WVs + m * 64 + kg * 8);
      float4 w0 = wv[0], w1 = wv[1];
      acc[0] += wa * w0.x; acc[1] += wa * w0.y; acc[2] += wa * w0.z; acc[3] += wa * w0.w;
      acc[4] += wa * w1.x; acc[5] += wa * w1.y; acc[6] += wa * w1.z; acc[7] += wa * w1.w;
    }
    #pragma unroll
    for (int j = 0; j < 8; j++) WAVT[(kg * 8 + j) * 64 + h] = acc[j];
    if (w2 < 64) {               // bAV = bA + WA @ bV
      float a = bA[w2];
      #pragma unroll
      for (int k = 0; k < 64; k++) a += WAs[w2 * 65 + k] * bVs[k];
      bAVs[w2] = a;
    }
  } else {
    // combine: batch b handled by 16 lanes, each lane owns 4 h's
    int b = t >> 4, i = t & 15;
    const float* Mb_ = Ml + b * NCH;
    const float* Sb_ = Sl + b * NCH;
    float mb = -1e30f;
    #pragma unroll
    for (int cc = 0; cc < NCH; cc++) mb = fmaxf(mb, Mb_[cc]);
    float we[NCH];
    float ssum = 0.f;
    #pragma unroll
    for (int cc = 0; cc < NCH; cc++) {
      we[cc] = expf(Mb_[cc] - mb);
      ssum += Sb_[cc] * we[cc];
    }
    float isb = 1.0f / ssum;
    float a0 = 0.f, a1 = 0.f, a2 = 0.f, a3 = 0.f;
    #pragma unroll 4
    for (int cc = 0; cc < NCH; cc++) {
      const float* vp = ws + WS_V + (size_t)(b * NCH + cc) * 64 + i;
      float wgt = we[cc];
      a0 += wgt * vp[0];  a1 += wgt * vp[16];
      a2 += wgt * vp[32]; a3 += wgt * vp[48];
    }
    st[b * STS + i]      = a0 * isb;
    st[b * STS + i + 16] = a1 * isb;
    st[b * STS + i + 32] = a2 * isb;
    st[b * STS + i + 48] = a3 * isb;
  }
  __syncthreads();

  // ---- stage 2: rounds ----
  const int bb = t >> 6;         // wave-uniform batch row (and bb+16)
  const int hg = t & 63;
  float wv_[64];                 // this thread's WAVT column (static idx)
  #pragma unroll
  for (int k = 0; k < 64; k++) wv_[k] = WAVT[k * 64 + hg];
  const float bav = bAVs[hg];

  for (int r = 0; r < 4; r++) {
    float a0 = bav, a1 = bav;
    #pragma unroll
    for (int k = 0; k < 64; k += 4) {
      float4 v0 = *(const float4*)(st + bb * STS + k);        // broadcast
      float4 v1 = *(const float4*)(st + (bb + 16) * STS + k); // broadcast
      a0 += v0.x * wv_[k] + v0.y * wv_[k + 1] + v0.z * wv_[k + 2] + v0.w * wv_[k + 3];
      a1 += v1.x * wv_[k] + v1.y * wv_[k + 1] + v1.z * wv_[k + 2] + v1.w * wv_[k + 3];
    }
    zs[bb * STS + hg] = a0;
    zs[(bb + 16) * STS + hg] = a1;
    __syncthreads();
    if (t < 64) {
      float s1 = 0.f;
      #pragma unroll
      for (int b2 = 0; b2 < BB; b2++) s1 += zs[b2 * STS + t];
      float mu = s1 * (1.0f / BB);
      float s2 = 0.f;
      #pragma unroll
      for (int b2 = 0; b2 < BB; b2++) {
        float d = zs[b2 * STS + t] - mu;
        s2 += d * d;
      }
      float inv = gammas[t] / sqrtf(s2 * (1.0f / BB) + BN_EPS);
      scs[t] = inv;
      shs[t] = betas[t] - mu * inv;
    }
    __syncthreads();
    for (int e = t; e < BB * 64; e += 1024) {
      int b2 = e >> 6, hh = e & 63;
      st[b2 * STS + hh] = fmaxf(zs[b2 * STS + hh] * scs[hh] + shs[hh], 0.f);
    }
    __syncthreads();
  }

  // ---- heads: 32 lanes per batch, shuffle reduce ----
  {
    int b = t >> 5, i = t & 31;
    float v0 = st[b * STS + i], v1 = st[b * STS + i + 32];
    float pm = v0 * wmus[i] + v1 * wmus[i + 32];
    float ps = v0 * wsigs[i] + v1 * wsigs[i + 32];
    pm += __shfl_down(pm, 16); ps += __shfl_down(ps, 16);
    pm += __shfl_down(pm, 8);  ps += __shfl_down(ps, 8);
    pm += __shfl_down(pm, 4);  ps += __shfl_down(ps, 4);
    pm += __shfl_down(pm, 2);  ps += __shfl_down(ps, 2);
    pm += __shfl_down(pm, 1);  ps += __shfl_down(ps, 1);
    if (i == 0) {
      float sg = ps + bsig[0];
      out[b] = pm + bmu[0];
      out[BB + b] = sg * sg + 0.01f;
    }
  }
}

// ================================================================ launch
extern "C" void kernel_launch(void* const* d_in, const int* in_sizes, int n_in,
                              void* d_out, int out_size, void* d_ws, size_t ws_size,
                              hipStream_t stream) {
  const float* xx   = (const float*)d_in[0];
  const float* yy   = (const float*)d_in[1];
  const float* oxx  = (const float*)d_in[2];
  const float* W1   = (const float*)d_in[3];
  const float* b1   = (const float*)d_in[4];
  const float* W2   = (const float*)d_in[5];
  const float* b2   = (const float*)d_in[6];
  const float* Wenc = (const float*)d_in[7];
  const float* benc = (const float*)d_in[8];
  // d_in[9]=WQ, [10]=bQ, [15]=wQKq, [17]=bQK: provably unused (the
  // i-dependent score term is constant over the softmax axis; bK·wQKk
  // cancels too, so d_in[12]=bK is also unused).
  const float* WK   = (const float*)d_in[11];
  const float* WV   = (const float*)d_in[13];
  const float* bV   = (const float*)d_in[14];
  const float* wQKk = (const float*)d_in[16];
  const float* WA   = (const float*)d_in[18];
  const float* bA   = (const float*)d_in[19];
  const float* gamma= (const float*)d_in[20];
  const float* beta = (const float*)d_in[21];
  const float* Wmu  = (const float*)d_in[22];
  const float* bmu  = (const float*)d_in[23];
  const float* Wsig = (const float*)d_in[24];
  const float* bsig = (const float*)d_in[25];

  float* ws  = (float*)d_ws;
  float* out = (float*)d_out;

  k_main<<<BB * NCH, 256, 0, stream>>>(xx, yy, oxx, W1, b1, W2, b2, Wenc, benc,
                                       WK, wQKk, ws);
  k_post<<<1, 1024, 0, stream>>>(ws, WV, bV, WA, bA, gamma, beta,
                                 Wmu, bmu, Wsig, bsig, out);
}